// Round 6
// baseline (77.164 us; speedup 1.0000x reference)
//
#include <hip/hip_runtime.h>
#include <math.h>

#define BS 4
#define LQ 128
#define IMG 256
#define NPIX (IMG*IMG)
#define NQ 4
#define NSLICE 8
#define SLICE_PIX (NPIX/NSLICE)   // 8192
#define SLICE_F4 (SLICE_PIX/4)    // 2048
#define CAP 512
#define NBLK (BS*(LQ/NQ)*NSLICE)  // 1024

__device__ __forceinline__ bool lessVI(float v1, int i1, float v2, int i2) {
    return (v1 < v2) || (v1 == v2 && i1 < i2);
}

#define CE8(WV, WI, a, c)                                                     \
    do {                                                                      \
        if (lessVI((WV)[c], (WI)[c], (WV)[a], (WI)[a])) {                     \
            float tv_ = (WV)[a]; (WV)[a] = (WV)[c]; (WV)[c] = tv_;            \
            int   ti_ = (WI)[a]; (WI)[a] = (WI)[c]; (WI)[c] = ti_;            \
        }                                                                     \
    } while (0)

// merge two sorted-ascending 8-lists -> sorted 8 smallest of 16 (static idx)
#define MERGE8(AV, AI, BV, BI, OV, OI)                                        \
    do {                                                                      \
        _Pragma("unroll")                                                     \
        for (int k_ = 0; k_ < 8; ++k_) {                                      \
            if (lessVI((AV)[k_], (AI)[k_], (BV)[7-k_], (BI)[7-k_])) {         \
                (OV)[k_] = (AV)[k_]; (OI)[k_] = (AI)[k_];                     \
            } else { (OV)[k_] = (BV)[7-k_]; (OI)[k_] = (BI)[7-k_]; }          \
        }                                                                     \
        CE8(OV, OI, 0, 4); CE8(OV, OI, 1, 5); CE8(OV, OI, 2, 6); CE8(OV, OI, 3, 7); \
        CE8(OV, OI, 0, 2); CE8(OV, OI, 1, 3); CE8(OV, OI, 4, 6); CE8(OV, OI, 5, 7); \
        CE8(OV, OI, 0, 1); CE8(OV, OI, 2, 3); CE8(OV, OI, 4, 5); CE8(OV, OI, 6, 7); \
    } while (0)

// 1024 blocks x 512 threads. Block = (batch b, query-quad qg, slice sl).
// A: tau_q = exact 8th-smallest of 1024 coalesced samples (sorting network +
//    wave bitonic; tau >= slice's true 8th-smallest).
// B: scan slice once, 4 sims/pixel; wave-aggregated ballot append of s<=tau.
// C: exact lexicographic top-8 per (query,slice) -> ws (sorted).
// Last-arriving block (device ticket) merges 8 slice lists and computes loss.
__global__ __launch_bounds__(512)
void fused_kernel(const float* __restrict__ pred,
                  const float* __restrict__ imgs,
                  float2* __restrict__ ws,
                  int* __restrict__ counter,
                  float* __restrict__ out) {
    __shared__ float pool[NQ][3];
    __shared__ float tau8[8];
    __shared__ float Tq[NQ];
    __shared__ int   cnt[NQ];
    __shared__ float lv[NQ][CAP];
    __shared__ int   li[NQ][CAP];
    __shared__ float mv[NQ][2][8];
    __shared__ int   mi[NQ][2][8];
    __shared__ int   lastflag;
    __shared__ float red[512];

    const int bid = blockIdx.x;
    // XCD swizzle: bid%8 ~ XCD; 2 XCD slots per batch -> image L2-resident.
    const int b  = (bid & 7) >> 1;
    const int u  = bid >> 3;
    const int sl = u & (NSLICE - 1);
    const int qg = (u >> 3) | ((bid & 1) << 4);     // [0,32)
    const int tid = threadIdx.x;
    const int qi = tid >> 7;                        // query in group [0,4)
    const int st = tid & 127;
    const int wid  = tid >> 6;
    const int lane = tid & 63;
    const unsigned long long lmask = (1ull << lane) - 1ull;

    if (tid < NQ) cnt[tid] = 0;

    // pooled color (reshape quirk: flat row n = l*BS + b of preds(bs*L,2))
    const int l  = qg * NQ + qi;
    const int n  = l * BS + b;
    const int pb = n >> 7;
    const int pl = n & (LQ - 1);
    const float gx = pred[(pb * LQ + pl) * 8 + 0];
    const float gy = pred[(pb * LQ + pl) * 8 + 1];
    const int ix = (int)fminf(fmaxf(rintf(gx * 256.0f - 0.5f), 0.0f), 255.0f);
    const int iy = (int)fminf(fmaxf(rintf(gy * 256.0f - 0.5f), 0.0f), 255.0f);
    const float* img = imgs + b * 3 * NPIX;
    const int pc = iy * IMG + ix;
    const float c0 = img[pc];
    const float c1 = img[NPIX + pc];
    const float c2 = img[2 * NPIX + pc];
    if (st == 0) { pool[qi][0] = c0; pool[qi][1] = c1; pool[qi][2] = c2; }

    // ---- Phase A: 8 coalesced samples/thread -> branchless sort-8 network
    float tb[8];
#pragma unroll
    for (int j = 0; j < 8; ++j) {
        const int p = sl * SLICE_PIX + j * 1024 + st;
        tb[j] = fabsf(img[p] - c0) + fabsf(img[NPIX + p] - c1)
              + fabsf(img[2 * NPIX + p] - c2);
    }
#define CEV(a, c) do { float lo = fminf(tb[a], tb[c]); float hi = fmaxf(tb[a], tb[c]); tb[a] = lo; tb[c] = hi; } while (0)
    CEV(0,1); CEV(2,3); CEV(4,5); CEV(6,7);
    CEV(0,2); CEV(1,3); CEV(4,6); CEV(5,7);
    CEV(1,2); CEV(5,6);
    CEV(0,4); CEV(1,5); CEV(2,6); CEV(3,7);
    CEV(2,4); CEV(3,5);
    CEV(1,2); CEV(3,4); CEV(5,6);
    // values-only wave bitonic merge -> lane 0 holds wave's sorted top-8
#pragma unroll
    for (int off = 1; off < 64; off <<= 1) {
        float ov[8];
#pragma unroll
        for (int k = 0; k < 8; ++k) ov[k] = __shfl_xor(tb[k], off, 64);
        float w[8];
#pragma unroll
        for (int k = 0; k < 8; ++k) w[k] = fminf(tb[k], ov[7 - k]);
#define CEW(a, c) do { float lo = fminf(w[a], w[c]); float hi = fmaxf(w[a], w[c]); w[a] = lo; w[c] = hi; } while (0)
        CEW(0, 4); CEW(1, 5); CEW(2, 6); CEW(3, 7);
        CEW(0, 2); CEW(1, 3); CEW(4, 6); CEW(5, 7);
        CEW(0, 1); CEW(2, 3); CEW(4, 5); CEW(6, 7);
#undef CEW
#pragma unroll
        for (int k = 0; k < 8; ++k) tb[k] = w[k];
    }
#undef CEV
    if (lane == 0) tau8[wid] = tb[7];   // 8th smallest of this wave's 512
    __syncthreads();
    if (tid < NQ) {
        // >=8 sampled elements <= min of the two wave-8ths => valid upper
        // bound on the slice's true 8th smallest.
        Tq[tid] = fminf(tau8[2 * tid], tau8[2 * tid + 1]);
    }
    __syncthreads();

    float P0[NQ], P1[NQ], P2[NQ], T[NQ];
#pragma unroll
    for (int q = 0; q < NQ; ++q) {
        P0[q] = pool[q][0]; P1[q] = pool[q][1]; P2[q] = pool[q][2];
        T[q] = Tq[q];
    }

    // ---- Phase B: scan slice once; wave-aggregated candidate append
    const float4* i0 = (const float4*)img;
    const float4* i1 = (const float4*)(img + NPIX);
    const float4* i2 = (const float4*)(img + 2 * NPIX);
#pragma unroll
    for (int it = 0; it < SLICE_F4 / 512; ++it) {
        const int q4 = sl * SLICE_F4 + it * 512 + tid;
        const float4 a0 = i0[q4];
        const float4 a1 = i1[q4];
        const float4 a2 = i2[q4];
        const int p = q4 * 4;
#pragma unroll
        for (int q = 0; q < NQ; ++q) {
            float s0 = fabsf(a0.x - P0[q]) + fabsf(a1.x - P1[q]) + fabsf(a2.x - P2[q]);
            float s1 = fabsf(a0.y - P0[q]) + fabsf(a1.y - P1[q]) + fabsf(a2.y - P2[q]);
            float s2 = fabsf(a0.z - P0[q]) + fabsf(a1.z - P1[q]) + fabsf(a2.z - P2[q]);
            float s3 = fabsf(a0.w - P0[q]) + fabsf(a1.w - P1[q]) + fabsf(a2.w - P2[q]);
            const bool h0 = s0 <= T[q], h1 = s1 <= T[q], h2 = s2 <= T[q], h3 = s3 <= T[q];
            if (__ballot(h0 | h1 | h2 | h3)) {
#define APPEND(H, S, PP)                                                      \
                do {                                                          \
                    const unsigned long long m_ = __ballot(H);                \
                    if (m_) {                                                 \
                        int base_ = 0;                                        \
                        if (lane == 0)                                        \
                            base_ = atomicAdd(&cnt[q], __popcll(m_));         \
                        base_ = __shfl(base_, 0, 64);                         \
                        if (H) {                                              \
                            const int pos_ = base_ + __popcll(m_ & lmask);    \
                            if (pos_ < CAP) { lv[q][pos_] = (S); li[q][pos_] = (PP); } \
                        }                                                     \
                    }                                                         \
                } while (0)
                APPEND(h0, s0, p + 0);
                APPEND(h1, s1, p + 1);
                APPEND(h2, s2, p + 2);
                APPEND(h3, s3, p + 3);
#undef APPEND
            }
        }
    }
    __syncthreads();

    // ---- Phase C: exact top-8 per query; 2 waves per query
    {
        const int q    = wid >> 1;
        const int half = wid & 1;
        const int nels = min(cnt[q], CAP);
        float bv[8]; int bi[8];
#pragma unroll
        for (int k = 0; k < 8; ++k) { bv[k] = 3.0e38f; bi[k] = 0x7FFFFFFF; }
        for (int c = half * 64 + lane; c < nels; c += 128) {
            const float v = lv[q][c];
            const int  id = li[q][c];
            if (lessVI(v, id, bv[7], bi[7])) {
                bv[7] = v; bi[7] = id;
#pragma unroll
                for (int k = 7; k > 0; --k) {
                    if (lessVI(bv[k], bi[k], bv[k - 1], bi[k - 1])) {
                        float tv = bv[k]; bv[k] = bv[k - 1]; bv[k - 1] = tv;
                        int   ti = bi[k]; bi[k] = bi[k - 1]; bi[k - 1] = ti;
                    }
                }
            }
        }
        // wave bitonic merge with (val, idx)
#pragma unroll
        for (int off = 1; off < 64; off <<= 1) {
            float ov[8]; int oi[8];
#pragma unroll
            for (int k = 0; k < 8; ++k) {
                ov[k] = __shfl_xor(bv[k], off, 64);
                oi[k] = __shfl_xor(bi[k], off, 64);
            }
            float w[8]; int wi[8];
#pragma unroll
            for (int k = 0; k < 8; ++k) {
                if (lessVI(bv[k], bi[k], ov[7 - k], oi[7 - k])) { w[k] = bv[k];     wi[k] = bi[k]; }
                else                                            { w[k] = ov[7 - k]; wi[k] = oi[7 - k]; }
            }
            CE8(w, wi, 0, 4); CE8(w, wi, 1, 5); CE8(w, wi, 2, 6); CE8(w, wi, 3, 7);
            CE8(w, wi, 0, 2); CE8(w, wi, 1, 3); CE8(w, wi, 4, 6); CE8(w, wi, 5, 7);
            CE8(w, wi, 0, 1); CE8(w, wi, 2, 3); CE8(w, wi, 4, 5); CE8(w, wi, 6, 7);
#pragma unroll
            for (int k = 0; k < 8; ++k) { bv[k] = w[k]; bi[k] = wi[k]; }
        }
        if (lane == 0) {
#pragma unroll
            for (int k = 0; k < 8; ++k) { mv[q][half][k] = bv[k]; mi[q][half][k] = bi[k]; }
        }
    }
    __syncthreads();

    // merge the two halves, write sorted 8 to ws[(mq*NSLICE + sl)*8 ..]
    if (st == 0) {
        float av[8], bv2[8], ov[8]; int ai[8], bi2[8], oi[8];
#pragma unroll
        for (int k = 0; k < 8; ++k) {
            av[k] = mv[qi][0][k]; ai[k] = mi[qi][0][k];
            bv2[k] = mv[qi][1][k]; bi2[k] = mi[qi][1][k];
        }
        MERGE8(av, ai, bv2, bi2, ov, oi);
        const int mq = b * LQ + qg * NQ + qi;
        float2* o = ws + (mq * NSLICE + sl) * 8;
#pragma unroll
        for (int k = 0; k < 8; ++k) {
            float2 e; e.x = ov[k]; e.y = __int_as_float(oi[k]);
            o[k] = e;
        }
    }
    __syncthreads();

    // ---- device-scope ticket: last arrival does the loss epilogue
    if (tid == 0) {
        __threadfence();
        const int t = atomicAdd(counter, 1);
        lastflag = ((t % NBLK) == (NBLK - 1)) ? 1 : 0;
    }
    __syncthreads();
    if (!lastflag) return;
    __threadfence();

    // epilogue: thread t -> (b2, l2); merge 8 sorted slice lists, min-dist
    {
        const int b2 = tid >> 7;
        const int l2 = tid & (LQ - 1);
        float v = 0.0f;
        if (l2 >= 1) {
            const int mq = b2 * LQ + (l2 - 1);
            const float2* base = ws + mq * (NSLICE * 8);
            float fv[8]; int fi[8];
#pragma unroll
            for (int k = 0; k < 8; ++k) {
                const float2 e = base[k];
                fv[k] = e.x; fi[k] = __float_as_int(e.y);
            }
#pragma unroll
            for (int s2 = 1; s2 < NSLICE; ++s2) {
                float av[8], ov[8]; int ai[8], oi[8];
#pragma unroll
                for (int k = 0; k < 8; ++k) {
                    const float2 e = base[s2 * 8 + k];
                    av[k] = e.x; ai[k] = __float_as_int(e.y);
                }
                MERGE8(fv, fi, av, ai, ov, oi);
#pragma unroll
                for (int k = 0; k < 8; ++k) { fv[k] = ov[k]; fi[k] = oi[k]; }
            }
            const float qx = pred[(b2 * LQ + l2) * 8 + 0];
            const float qy = pred[(b2 * LQ + l2) * 8 + 1];
            float best = 3.0e38f;
#pragma unroll
            for (int k = 0; k < 8; ++k) {
                const int id = fi[k];
                const float tx = (float)(id & (IMG - 1)) * (1.0f / IMG);
                const float ty = (float)(id >> 8)        * (1.0f / IMG);
                const float dx = qx - tx;
                const float dy = qy - ty;
                best = fminf(best, sqrtf(dx * dx + dy * dy));
            }
            v = best;
        }
        red[tid] = v;
        __syncthreads();
        for (int s = 256; s > 0; s >>= 1) {
            if (tid < s) red[tid] += red[tid + s];
            __syncthreads();
        }
        if (tid == 0) out[0] = red[0] * (1.0f / (BS * (LQ - 1)));
    }
}

extern "C" void kernel_launch(void* const* d_in, const int* in_sizes, int n_in,
                              void* d_out, int out_size, void* d_ws, size_t ws_size,
                              hipStream_t stream) {
    const float* pred = (const float*)d_in[0];   // (4,128,8) f32
    const float* imgs = (const float*)d_in[1];   // (4,3,256,256) f32
    float* out = (float*)d_out;                  // scalar f32
    int* counter = (int*)d_ws;                   // 4B ticket counter
    float2* ws = (float2*)((char*)d_ws + 256);   // 512*8*8 float2 = 256 KB

    hipMemsetAsync(counter, 0, 4, stream);
    hipLaunchKernelGGL(fused_kernel, dim3(NBLK), dim3(512), 0, stream,
                       pred, imgs, ws, counter, out);
}

// Round 7
// 68.123 us; speedup vs baseline: 1.1327x; 1.1327x over previous
//
#include <hip/hip_runtime.h>
#include <math.h>

#ifndef __has_builtin
#define __has_builtin(x) 0
#endif

#define BS 4
#define LQ 128
#define IMG 256
#define NPIX (IMG*IMG)
#define NQ 4
#define NSLICE 8
#define SLICE_PIX (NPIX/NSLICE)   // 8192
#define SLICE_U4 (SLICE_PIX/4)    // 2048 uint4 per slice
#define RING 12
#define CAP 256
#define NBLK (BS*(LQ/NQ)*NSLICE)  // 1024

__device__ __forceinline__ unsigned sad3_u8(unsigned a, unsigned b) {
#if __has_builtin(__builtin_amdgcn_sad_u8)
    return __builtin_amdgcn_sad_u8(a, b, 0u);   // byte3 is 0 on both
#else
    unsigned s = 0;
#pragma unroll
    for (int i = 0; i < 3; ++i) {
        int d = (int)((a >> (8 * i)) & 255u) - (int)((b >> (8 * i)) & 255u);
        s += (unsigned)(d < 0 ? -d : d);
    }
    return s;
#endif
}

__device__ __forceinline__ bool lessVI(float v1, int i1, float v2, int i2) {
    return (v1 < v2) || (v1 == v2 && i1 < i2);
}

#define CE8(WV, WI, a, c)                                                     \
    do {                                                                      \
        if (lessVI((WV)[c], (WI)[c], (WV)[a], (WI)[a])) {                     \
            float tv_ = (WV)[a]; (WV)[a] = (WV)[c]; (WV)[c] = tv_;            \
            int   ti_ = (WI)[a]; (WI)[a] = (WI)[c]; (WI)[c] = ti_;            \
        }                                                                     \
    } while (0)

// merge two sorted-ascending 8-lists -> sorted 8 smallest of 16 (static idx)
#define MERGE8(AV, AI, BV, BI, OV, OI)                                        \
    do {                                                                      \
        _Pragma("unroll")                                                     \
        for (int k_ = 0; k_ < 8; ++k_) {                                      \
            if (lessVI((AV)[k_], (AI)[k_], (BV)[7-k_], (BI)[7-k_])) {         \
                (OV)[k_] = (AV)[k_]; (OI)[k_] = (AI)[k_];                     \
            } else { (OV)[k_] = (BV)[7-k_]; (OI)[k_] = (BI)[7-k_]; }          \
        }                                                                     \
        CE8(OV, OI, 0, 4); CE8(OV, OI, 1, 5); CE8(OV, OI, 2, 6); CE8(OV, OI, 3, 7); \
        CE8(OV, OI, 0, 2); CE8(OV, OI, 1, 3); CE8(OV, OI, 4, 6); CE8(OV, OI, 5, 7); \
        CE8(OV, OI, 0, 1); CE8(OV, OI, 2, 3); CE8(OV, OI, 4, 5); CE8(OV, OI, 6, 7); \
    } while (0)

// Quantize image to u8 RGB packed in one u32 per pixel (4x fewer bytes to
// stream in the scan; exactness restored by fp32 recheck of candidates).
__global__ __launch_bounds__(512)
void quant_kernel(const float* __restrict__ imgs, unsigned* __restrict__ wpix) {
    const int g = blockIdx.x * 512 + threadIdx.x;     // 512 blocks
    const int b = g >> 16;
    const int p = g & (NPIX - 1);
    const float* base = imgs + b * 3 * NPIX + p;
    const unsigned r  = (unsigned)rintf(base[0]        * 255.0f);
    const unsigned gg = (unsigned)rintf(base[NPIX]     * 255.0f);
    const unsigned bb = (unsigned)rintf(base[2 * NPIX] * 255.0f);
    wpix[g] = r | (gg << 8) | (bb << 16);
}

// 1024 blocks x 512 threads. Block = (batch b, query-quad qg, slice sl).
// A: integer tau = exact 8th-smallest of 512 sampled u8-sims per wave
//    (conservative: test  sim_u8 <= tau+6  provably catches all true top-8).
// B: stream slice as u32 pixels; 1 v_sad_u8 + cmp per (pixel,query); hits go
//    to a per-thread private 12-slot LDS ring (no atomics, no readback).
// C: fp32 exact recheck of ring entries -> per-query list -> exact wave top-8.
// Ticket: last block merges 8 slice lists per query and computes the loss.
__global__ __launch_bounds__(512)
void fused_kernel(const float* __restrict__ pred,
                  const float* __restrict__ imgs,
                  const unsigned* __restrict__ wpix,
                  float2* __restrict__ ws,
                  int* __restrict__ counter,
                  float* __restrict__ out) {
    __shared__ float    pool[NQ][3];
    __shared__ unsigned tau8[8];
    __shared__ int      cnt_q[NQ];
    __shared__ unsigned slots[512 * RING];
    __shared__ float    lv[NQ][CAP];
    __shared__ int      li[NQ][CAP];
    __shared__ float    mv[NQ][2][8];
    __shared__ int      mi[NQ][2][8];
    __shared__ int      lastflag;
    __shared__ float    red[512];

    const int bid = blockIdx.x;
    // XCD swizzle: bid%8 ~ XCD; 2 XCD slots per batch -> u32 image L2-resident.
    const int b  = (bid & 7) >> 1;
    const int u  = bid >> 3;
    const int sl = u & (NSLICE - 1);
    const int qg = (u >> 3) | ((bid & 1) << 4);     // [0,32)
    const int tid = threadIdx.x;
    const int qi = tid >> 7;                        // this thread's query [0,4)
    const int st = tid & 127;
    const int wid  = tid >> 6;
    const int lane = tid & 63;

    if (tid < NQ) cnt_q[tid] = 0;

    // pooled color (reshape quirk: flat row n = l*BS + b of preds(bs*L,2))
    const int l  = qg * NQ + qi;
    const int n  = l * BS + b;
    const int pb = n >> 7;
    const int pl = n & (LQ - 1);
    const float gx = pred[(pb * LQ + pl) * 8 + 0];
    const float gy = pred[(pb * LQ + pl) * 8 + 1];
    const int ix = (int)fminf(fmaxf(rintf(gx * 256.0f - 0.5f), 0.0f), 255.0f);
    const int iy = (int)fminf(fmaxf(rintf(gy * 256.0f - 0.5f), 0.0f), 255.0f);
    const float* img = imgs + b * 3 * NPIX;
    const int pc = iy * IMG + ix;
    const float c0 = img[pc];
    const float c1 = img[NPIX + pc];
    const float c2 = img[2 * NPIX + pc];
    if (st == 0) { pool[qi][0] = c0; pool[qi][1] = c1; pool[qi][2] = c2; }
    const unsigned Qme = (unsigned)rintf(c0 * 255.0f)
                       | ((unsigned)rintf(c1 * 255.0f) << 8)
                       | ((unsigned)rintf(c2 * 255.0f) << 16);

    const unsigned* wp = wpix + b * NPIX;

    // ---- Phase A: 8 coalesced u32 samples -> branchless sort-8 (uint)
    unsigned tb[8];
#pragma unroll
    for (int j = 0; j < 8; ++j) {
        const int p = sl * SLICE_PIX + j * 1024 + st;
        tb[j] = sad3_u8(wp[p], Qme);
    }
#define CEV(a, c) do { unsigned lo = min(tb[a], tb[c]); unsigned hi = max(tb[a], tb[c]); tb[a] = lo; tb[c] = hi; } while (0)
    CEV(0,1); CEV(2,3); CEV(4,5); CEV(6,7);
    CEV(0,2); CEV(1,3); CEV(4,6); CEV(5,7);
    CEV(1,2); CEV(5,6);
    CEV(0,4); CEV(1,5); CEV(2,6); CEV(3,7);
    CEV(2,4); CEV(3,5);
    CEV(1,2); CEV(3,4); CEV(5,6);
#undef CEV
    // values-only wave bitonic merge (uint)
#pragma unroll
    for (int off = 1; off < 64; off <<= 1) {
        unsigned ov[8];
#pragma unroll
        for (int k = 0; k < 8; ++k) ov[k] = (unsigned)__shfl_xor((int)tb[k], off, 64);
        unsigned w[8];
#pragma unroll
        for (int k = 0; k < 8; ++k) w[k] = min(tb[k], ov[7 - k]);
#define CEW(a, c) do { unsigned lo = min(w[a], w[c]); unsigned hi = max(w[a], w[c]); w[a] = lo; w[c] = hi; } while (0)
        CEW(0, 4); CEW(1, 5); CEW(2, 6); CEW(3, 7);
        CEW(0, 2); CEW(1, 3); CEW(4, 6); CEW(5, 7);
        CEW(0, 1); CEW(2, 3); CEW(4, 5); CEW(6, 7);
#undef CEW
#pragma unroll
        for (int k = 0; k < 8; ++k) tb[k] = w[k];
    }
    if (lane == 0) tau8[wid] = tb[7];   // exact 8th smallest of wave's 512
    __syncthreads();

    unsigned Qu[NQ], T6[NQ];
#pragma unroll
    for (int q = 0; q < NQ; ++q) {
        Qu[q] = (unsigned)rintf(pool[q][0] * 255.0f)
              | ((unsigned)rintf(pool[q][1] * 255.0f) << 8)
              | ((unsigned)rintf(pool[q][2] * 255.0f) << 16);
        // tau from whichever wave has the smaller 8th (valid subset bound);
        // +6 covers both-side quantization error -> provable superset.
        T6[q] = min(tau8[2 * q], tau8[2 * q + 1]) + 6u;
    }

    // ---- Phase B: stream slice (4 B/px); hits -> private LDS ring
    const uint4* p4 = (const uint4*)wp;
    const int slotbase = tid * RING;
    int cnt = 0;
#pragma unroll
    for (int it = 0; it < SLICE_U4 / 512; ++it) {
        const int idx = sl * SLICE_U4 + it * 512 + tid;
        const uint4 P = p4[idx];
        const int pbase = idx * 4;
#define PXQ(PV, J)                                                            \
        do {                                                                  \
            _Pragma("unroll")                                                 \
            for (int q = 0; q < NQ; ++q) {                                    \
                const unsigned su = sad3_u8((PV), Qu[q]);                     \
                if (su <= T6[q]) {                                            \
                    const int sidx = cnt < RING ? cnt : RING - 1;             \
                    slots[slotbase + sidx] =                                  \
                        (su << 18) | ((unsigned)q << 16) | (unsigned)(pbase + (J)); \
                    ++cnt;                                                    \
                }                                                             \
            }                                                                 \
        } while (0)
        PXQ(P.x, 0); PXQ(P.y, 1); PXQ(P.z, 2); PXQ(P.w, 3);
#undef PXQ
    }
    __syncthreads();

    // ---- exact fp32 recheck of ring entries -> per-query candidate lists
    {
        const int kc = cnt < RING ? cnt : RING;
        for (int k = 0; k < kc; ++k) {
            const unsigned s = slots[slotbase + k];
            const int pix = (int)(s & 0xFFFFu);
            const int q   = (int)((s >> 16) & 3u);
            const float d0 = fabsf(img[pix]            - pool[q][0]);
            const float d1 = fabsf(img[NPIX + pix]     - pool[q][1]);
            const float d2 = fabsf(img[2 * NPIX + pix] - pool[q][2]);
            const float sim = d0 + d1 + d2;
            const int pos = atomicAdd(&cnt_q[q], 1);
            if (pos < CAP) { lv[q][pos] = sim; li[q][pos] = pix; }
        }
    }
    __syncthreads();

    // ---- Phase C: exact top-8 per query; 2 waves per query
    {
        const int q    = wid >> 1;
        const int half = wid & 1;
        const int nels = min(cnt_q[q], CAP);
        float bv[8]; int bi[8];
#pragma unroll
        for (int k = 0; k < 8; ++k) { bv[k] = 3.0e38f; bi[k] = 0x7FFFFFFF; }
        for (int c = half * 64 + lane; c < nels; c += 128) {
            const float v = lv[q][c];
            const int  id = li[q][c];
            if (lessVI(v, id, bv[7], bi[7])) {
                bv[7] = v; bi[7] = id;
#pragma unroll
                for (int k = 7; k > 0; --k) {
                    if (lessVI(bv[k], bi[k], bv[k - 1], bi[k - 1])) {
                        float tv = bv[k]; bv[k] = bv[k - 1]; bv[k - 1] = tv;
                        int   ti = bi[k]; bi[k] = bi[k - 1]; bi[k - 1] = ti;
                    }
                }
            }
        }
        // wave bitonic merge with (val, idx)
#pragma unroll
        for (int off = 1; off < 64; off <<= 1) {
            float ov[8]; int oi[8];
#pragma unroll
            for (int k = 0; k < 8; ++k) {
                ov[k] = __shfl_xor(bv[k], off, 64);
                oi[k] = __shfl_xor(bi[k], off, 64);
            }
            float w[8]; int wi[8];
#pragma unroll
            for (int k = 0; k < 8; ++k) {
                if (lessVI(bv[k], bi[k], ov[7 - k], oi[7 - k])) { w[k] = bv[k];     wi[k] = bi[k]; }
                else                                            { w[k] = ov[7 - k]; wi[k] = oi[7 - k]; }
            }
            CE8(w, wi, 0, 4); CE8(w, wi, 1, 5); CE8(w, wi, 2, 6); CE8(w, wi, 3, 7);
            CE8(w, wi, 0, 2); CE8(w, wi, 1, 3); CE8(w, wi, 4, 6); CE8(w, wi, 5, 7);
            CE8(w, wi, 0, 1); CE8(w, wi, 2, 3); CE8(w, wi, 4, 5); CE8(w, wi, 6, 7);
#pragma unroll
            for (int k = 0; k < 8; ++k) { bv[k] = w[k]; bi[k] = wi[k]; }
        }
        if (lane == 0) {
#pragma unroll
            for (int k = 0; k < 8; ++k) { mv[q][half][k] = bv[k]; mi[q][half][k] = bi[k]; }
        }
    }
    __syncthreads();

    // merge the two halves, write sorted 8 to ws[(mq*NSLICE + sl)*8 ..]
    if (st == 0) {
        float av[8], bv2[8], ov[8]; int ai[8], bi2[8], oi[8];
#pragma unroll
        for (int k = 0; k < 8; ++k) {
            av[k]  = mv[qi][0][k]; ai[k]  = mi[qi][0][k];
            bv2[k] = mv[qi][1][k]; bi2[k] = mi[qi][1][k];
        }
        MERGE8(av, ai, bv2, bi2, ov, oi);
        const int mq = b * LQ + qg * NQ + qi;
        float2* o = ws + (mq * NSLICE + sl) * 8;
#pragma unroll
        for (int k = 0; k < 8; ++k) {
            float2 e; e.x = ov[k]; e.y = __int_as_float(oi[k]);
            o[k] = e;
        }
    }
    __syncthreads();

    // ---- device-scope ticket: last arrival does the loss epilogue
    if (tid == 0) {
        __threadfence();
        const int t = atomicAdd(counter, 1);
        lastflag = ((t % NBLK) == (NBLK - 1)) ? 1 : 0;
    }
    __syncthreads();
    if (!lastflag) return;
    __threadfence();

    // epilogue: thread t -> (b2, l2); merge 8 sorted slice lists, min-dist
    {
        const int b2 = tid >> 7;
        const int l2 = tid & (LQ - 1);
        float v = 0.0f;
        if (l2 >= 1) {
            const int mq = b2 * LQ + (l2 - 1);
            const float2* base = ws + mq * (NSLICE * 8);
            float fv[8]; int fi[8];
#pragma unroll
            for (int k = 0; k < 8; ++k) {
                const float2 e = base[k];
                fv[k] = e.x; fi[k] = __float_as_int(e.y);
            }
#pragma unroll
            for (int s2 = 1; s2 < NSLICE; ++s2) {
                float av[8], ov[8]; int ai[8], oi[8];
#pragma unroll
                for (int k = 0; k < 8; ++k) {
                    const float2 e = base[s2 * 8 + k];
                    av[k] = e.x; ai[k] = __float_as_int(e.y);
                }
                MERGE8(fv, fi, av, ai, ov, oi);
#pragma unroll
                for (int k = 0; k < 8; ++k) { fv[k] = ov[k]; fi[k] = oi[k]; }
            }
            const float qx = pred[(b2 * LQ + l2) * 8 + 0];
            const float qy = pred[(b2 * LQ + l2) * 8 + 1];
            float best = 3.0e38f;
#pragma unroll
            for (int k = 0; k < 8; ++k) {
                const int id = fi[k];
                const float tx = (float)(id & (IMG - 1)) * (1.0f / IMG);
                const float ty = (float)(id >> 8)        * (1.0f / IMG);
                const float dx = qx - tx;
                const float dy = qy - ty;
                best = fminf(best, sqrtf(dx * dx + dy * dy));
            }
            v = best;
        }
        red[tid] = v;
        __syncthreads();
        for (int s = 256; s > 0; s >>= 1) {
            if (tid < s) red[tid] += red[tid + s];
            __syncthreads();
        }
        if (tid == 0) out[0] = red[0] * (1.0f / (BS * (LQ - 1)));
    }
}

extern "C" void kernel_launch(void* const* d_in, const int* in_sizes, int n_in,
                              void* d_out, int out_size, void* d_ws, size_t ws_size,
                              hipStream_t stream) {
    const float* pred = (const float*)d_in[0];   // (4,128,8) f32
    const float* imgs = (const float*)d_in[1];   // (4,3,256,256) f32
    float* out = (float*)d_out;                  // scalar f32

    int*      counter = (int*)d_ws;                              // 4 B ticket
    float2*   ws      = (float2*)((char*)d_ws + 256);            // 256 KB lists
    unsigned* wpix    = (unsigned*)((char*)d_ws + 512 * 1024);   // 1 MB u32 px

    hipMemsetAsync(counter, 0, 4, stream);
    hipLaunchKernelGGL(quant_kernel, dim3(512), dim3(512), 0, stream,
                       imgs, wpix);
    hipLaunchKernelGGL(fused_kernel, dim3(NBLK), dim3(512), 0, stream,
                       pred, imgs, wpix, ws, counter, out);
}